// Round 4
// baseline (607.178 us; speedup 1.0000x reference)
//
#include <hip/hip_runtime.h>

// Problem constants (from reference)
#define NUu 200000
#define NIi 100000
#define EE  600000
// D = H = 128

#define NB_USER 3125  // (NUu+63)/64
#define NB_ITEM 1563  // (NIi+63)/64

// Fixed-capacity neighbor buckets (replaces CSR entirely).
// deg ~ Binomial(600K, 1/200K) ~ Poisson(3) for user dsts, Poisson(6) for item
// dsts. P(deg >= 32) ~ 1e-27/node, P(deg >= 48) ~ 1e-30/node -> capacities are
// unreachable for any realistic input; guarded by skip + min() anyway.
#define CAP_U 32
#define CAP_I 48

// prep kernel grid sections
#define PB_BKT_U  586         // 586*1024 >= EE   (user-dst buckets)
#define PB_BKT    1172        // + item-dst buckets
#define PB_W      1428        // + 256 fuse_weights blocks
#define PB_BIAS   1428        // single bias block id
#define PB_CVU    1429        // conv-user start (12500 blocks)
#define PB_CVI    13929       // conv-item start (6250 blocks)
#define PB_END    20179

typedef short short8 __attribute__((ext_vector_type(8)));
typedef float floatx4 __attribute__((ext_vector_type(4)));
typedef float f32x4 __attribute__((ext_vector_type(4)));   // NT-capable vec

// float -> bf16 bits, round-to-nearest-even
__device__ __forceinline__ unsigned short f2bf(float f) {
  union { float f; unsigned int u; } v; v.f = f;
  unsigned int r = v.u + 0x7FFFu + ((v.u >> 16) & 1u);
  return (unsigned short)(r >> 16);
}
// bf16 pair (packed in u32) -> f32
__device__ __forceinline__ float bflo(unsigned int u) { return __uint_as_float(u << 16); }
__device__ __forceinline__ float bfhi(unsigned int u) { return __uint_as_float(u & 0xFFFF0000u); }

// ---------------------------------------------------------------------------
// prep: ONE launch fusing all preprocessing; the latency-bound random-atomic
// bucket blocks overlap with streaming conversion / weight-fusion blocks:
//   [0,586)        user-dst buckets: slot=atomicAdd(cnt_user[dst]); bkt[dst*32+slot]=src
//   [586,1172)     item-dst buckets (CAP 48)
//   [1172,1428)    fused weights W1=Wl@W2, W2=Wr@W2 -> bf16 MFMA B-frag layout
//                  elem = ((nt*8+ks)*64 + quad*16 + nlo)*8 + j,
//                  k = ks*32+quad*8+j, n = nt*16+nlo
//   {1428}         fused bias  bl@W2 + b2
//   [1429,13929)   x_user -> bf16 (NT loads: read-once fp32 must not evict xb)
//   [13929,20179)  x_item -> bf16
// Fallback (ws too small for bf16 arrays): launch only [0,1429).
// ---------------------------------------------------------------------------
__global__ __launch_bounds__(256) void prep(
    const int* __restrict__ esrc_iu, const int* __restrict__ edst_iu,
    int* __restrict__ cnt_user, int* __restrict__ bkt_user,
    const int* __restrict__ esrc_ui, const int* __restrict__ edst_ui,
    int* __restrict__ cnt_item, int* __restrict__ bkt_item,
    const float* __restrict__ Wl_iu, const float* __restrict__ Wr_iu,
    const float* __restrict__ Wl_ui, const float* __restrict__ Wr_ui,
    const float* __restrict__ W_user, const float* __restrict__ W_item,
    unsigned short* __restrict__ Wp_user, unsigned short* __restrict__ Wp_item,
    const float* __restrict__ bl_iu, const float* __restrict__ b_user,
    const float* __restrict__ bl_ui, const float* __restrict__ b_item,
    float* __restrict__ bias_user, float* __restrict__ bias_item,
    const float* __restrict__ x_user, const float* __restrict__ x_item,
    unsigned short* __restrict__ xb_user, unsigned short* __restrict__ xb_item)
{
  int b = blockIdx.x, t = threadIdx.x;
  if (b < PB_BKT) {
    // ---- neighbor buckets (hist + fill fused; no scan needed) ----
    bool uside = b < PB_BKT_U;
    const int* es = uside ? esrc_iu : esrc_ui;
    const int* ed = uside ? edst_iu : edst_ui;
    int* cnt      = uside ? cnt_user : cnt_item;
    int* bkt      = uside ? bkt_user : bkt_item;
    int cap       = uside ? CAP_U : CAP_I;
    int local     = uside ? b : b - PB_BKT_U;
    int idx = local * 1024 + t * 4;
    if (idx < EE) {                       // EE%4==0 -> whole int4 valid
      int4 s = *(const int4*)(es + idx);
      int4 d = *(const int4*)(ed + idx);
      int p0 = atomicAdd(&cnt[d.x], 1); if (p0 < cap) bkt[d.x * cap + p0] = s.x;
      int p1 = atomicAdd(&cnt[d.y], 1); if (p1 < cap) bkt[d.y * cap + p1] = s.y;
      int p2 = atomicAdd(&cnt[d.z], 1); if (p2 < cap) bkt[d.z * cap + p2] = s.z;
      int p3 = atomicAdd(&cnt[d.w], 1); if (p3 < cap) bkt[d.w * cap + p3] = s.w;
    }
  } else if (b < PB_W) {
    // ---- fused weights ----
    int flat = (b - PB_BKT) * 256 + t;    // 0..65535
    int h = flat & 127, d = (flat >> 7) & 127, m = flat >> 14;
    const float* A; const float* W; unsigned short* dst; int koff;
    switch (m) {
      case 0:  A = Wl_iu; W = W_user; dst = Wp_user; koff = 0;   break;
      case 1:  A = Wr_iu; W = W_user; dst = Wp_user; koff = 128; break;
      case 2:  A = Wl_ui; W = W_item; dst = Wp_item; koff = 0;   break;
      default: A = Wr_ui; W = W_item; dst = Wp_item; koff = 128; break;
    }
    float acc = 0.f;
    for (int k = 0; k < 128; ++k) acc += A[d * 128 + k] * W[k * 128 + h];
    int kg = koff + d;
    int ks = kg >> 5, quad = (kg >> 3) & 3, j = kg & 7;
    int nt = h >> 4, nlo = h & 15;
    dst[((nt * 8 + ks) * 64 + quad * 16 + nlo) * 8 + j] = f2bf(acc);
  } else if (b == PB_BIAS) {
    // ---- fused bias ----
    int pair = t >> 7, h = t & 127;
    const float* bl = pair ? bl_ui : bl_iu;
    const float* b2 = pair ? b_item : b_user;
    const float* W  = pair ? W_item : W_user;
    float* o        = pair ? bias_item : bias_user;
    float acc = b2[h];
    for (int k = 0; k < 128; ++k) acc += bl[k] * W[k * 128 + h];
    o[h] = acc;
  } else {
    // ---- fp32 -> bf16 conversion (exact block coverage) ----
    const float* src; unsigned short* dst; long base;
    if (b < PB_CVI) { src = x_user; dst = xb_user; base = (long)(b - PB_CVU) * 2048 + t * 8; }
    else            { src = x_item; dst = xb_item; base = (long)(b - PB_CVI) * 2048 + t * 8; }
    const f32x4* p4 = (const f32x4*)(src + base);
    f32x4 lo = __builtin_nontemporal_load(p4);
    f32x4 hi = __builtin_nontemporal_load(p4 + 1);
    uint4 p;
    p.x = (unsigned)f2bf(lo.x) | ((unsigned)f2bf(lo.y) << 16);
    p.y = (unsigned)f2bf(lo.z) | ((unsigned)f2bf(lo.w) << 16);
    p.z = (unsigned)f2bf(hi.x) | ((unsigned)f2bf(hi.y) << 16);
    p.w = (unsigned)f2bf(hi.z) | ((unsigned)f2bf(hi.w) << 16);
    *(uint4*)(dst + base) = p;
  }
}

// ---------------------------------------------------------------------------
// K3 v4: fused node kernel over fixed-capacity buckets (no CSR).
//  - deg = min(cnt[node], CAP); neighbor list at bkt + node*CAP (no rowp/window)
//  - BF=true: bf16 gather rows (256B), 77MB working set L3-resident
//  - epilogue: acc -> LDS (reusing the 16KB A buffer in 8-row halves) ->
//    coalesced f32x4 NT stores, 1024B contiguous per wave-instr (full 128B
//    lines -> no partial-line write amplification, true L3 bypass)
// mfma_f32_16x16x32_bf16 C/D: col=lane&15, row=(lane>>4)*4+reg   (m89/m91)
// ---------------------------------------------------------------------------
template<bool BF>
__global__ __launch_bounds__(256, 8) void fused_gemm(
    const void* __restrict__ xu_own, const void* __restrict__ xu_src,
    const int* __restrict__ cnt_u, const int* __restrict__ bkt_u,
    const unsigned short* __restrict__ Wp_u, const float* __restrict__ bias_u,
    const void* __restrict__ xi_own, const void* __restrict__ xi_src,
    const int* __restrict__ cnt_i, const int* __restrict__ bkt_i,
    const unsigned short* __restrict__ Wp_i, const float* __restrict__ bias_i,
    float* __restrict__ out)
{
  __shared__ __align__(16) uint4 ldsA4[1024];    // 16 KB packed A (half of K), reused by epilogue
  __shared__ int rb[64];                         // block node degrees
  int t = threadIdx.x;
  int b = blockIdx.x;

  const void* xown; const void* xsrc; const int* cntp; const int* bkt;
  const unsigned short* Wp; const float* bias; float* outbase; int nvalid; int node0; int cap;
  if (b < NB_USER) {
    xown = xu_own; xsrc = xu_src; cntp = cnt_u; bkt = bkt_u;
    Wp = Wp_u; bias = bias_u; outbase = out; nvalid = NUu; node0 = b * 64; cap = CAP_U;
  } else {
    xown = xi_own; xsrc = xi_src; cntp = cnt_i; bkt = bkt_i;
    Wp = Wp_i; bias = bias_i; outbase = out + (size_t)NUu * 128;
    nvalid = NIi; node0 = (b - NB_USER) * 64; cap = CAP_I;
  }

  // ---- phase 0: degrees ----
  if (t < 64) {
    int node = node0 + t;
    int c = node < nvalid ? cntp[node] : 0;
    rb[t] = c < cap ? c : cap;
  }

  // ---- phase 1: own-half (K=128..255) pack into swizzled A slots ----
  #pragma unroll
  for (int i = 0; i < 4; ++i) {
    int oid = t + i * 256;
    int m = oid >> 4;                            // node within block
    int oct = oid & 15;                          // 8-elem k-slice
    int node = node0 + m;
    uint4 p; p.x = 0u; p.y = 0u; p.z = 0u; p.w = 0u;
    if (node < nvalid) {
      if constexpr (BF) {
        p = *(const uint4*)((const unsigned short*)xown + (size_t)node * 128 + oct * 8);
      } else {
        const float4* p4 = (const float4*)((const float*)xown + (size_t)node * 128 + oct * 8);
        float4 lo = p4[0], hi = p4[1];
        p.x = (unsigned)f2bf(lo.x) | ((unsigned)f2bf(lo.y) << 16);
        p.y = (unsigned)f2bf(lo.z) | ((unsigned)f2bf(lo.w) << 16);
        p.z = (unsigned)f2bf(hi.x) | ((unsigned)f2bf(hi.y) << 16);
        p.w = (unsigned)f2bf(hi.z) | ((unsigned)f2bf(hi.w) << 16);
      }
    }
    int ks = oct >> 2, quad = oct & 3;
    int mt = m >> 4, mlo = m & 15;
    ldsA4[(mt * 4 + ks) * 64 + quad * 16 + (mlo ^ (oct & 7))] = p;
  }
  __syncthreads();

  // ---- phase 2: MFMA own half (k_global 128..255) ----
  int wave = t >> 6, lane = t & 63;
  int quadr = lane >> 4, mlor = lane & 15;
  floatx4 acc[8];
  #pragma unroll
  for (int i = 0; i < 8; ++i) acc[i] = (floatx4){0.f, 0.f, 0.f, 0.f};
  float bv[8];
  #pragma unroll
  for (int nt = 0; nt < 8; ++nt) bv[nt] = bias[nt * 16 + mlor];
  const short8* A = (const short8*)ldsA4;
  const short8* B = (const short8*)Wp;
  #pragma unroll
  for (int kk = 0; kk < 4; ++kk) {
    short8 af = A[(wave * 4 + kk) * 64 + quadr * 16 + (mlor ^ ((kk * 4 + quadr) & 7))];
    #pragma unroll
    for (int nt = 0; nt < 8; ++nt) {
      short8 bf = B[(nt * 8 + 4 + kk) * 64 + lane];
      acc[nt] = __builtin_amdgcn_mfma_f32_16x16x32_bf16(af, bf, acc[nt], 0, 0, 0);
    }
  }
  __syncthreads();                               // ldsA consumed, safe to refill

  // ---- phase 3: gather+mean over bucket lists, parity-split (32 lanes/node) ----
  #pragma unroll
  for (int i = 0; i < 8; ++i) {
    int oid = t + i * 256;
    int m = oid >> 5;
    int oct = oid & 31;
    int slice = oct & 15;
    int par = oct >> 4;
    int node = node0 + m;
    float a0=0,a1=0,a2=0,a3=0,a4=0,a5=0,a6=0,a7=0;
    int deg = rb[m];
    if (node < nvalid && deg > 0) {
      const int* bp = bkt + (size_t)node * cap;
      int k0 = slice * 8;
      int e = par;
      if constexpr (BF) {
        const unsigned short* xs = (const unsigned short*)xsrc;
        for (; e + 2 < deg; e += 4) {
          int s0 = bp[e], s1 = bp[e + 2];
          uint4 v0 = *(const uint4*)(xs + (size_t)s0 * 128 + k0);
          uint4 v1 = *(const uint4*)(xs + (size_t)s1 * 128 + k0);
          a0 += bflo(v0.x) + bflo(v1.x); a1 += bfhi(v0.x) + bfhi(v1.x);
          a2 += bflo(v0.y) + bflo(v1.y); a3 += bfhi(v0.y) + bfhi(v1.y);
          a4 += bflo(v0.z) + bflo(v1.z); a5 += bfhi(v0.z) + bfhi(v1.z);
          a6 += bflo(v0.w) + bflo(v1.w); a7 += bfhi(v0.w) + bfhi(v1.w);
        }
        if (e < deg) {
          int s = bp[e];
          uint4 v0 = *(const uint4*)(xs + (size_t)s * 128 + k0);
          a0 += bflo(v0.x); a1 += bfhi(v0.x);
          a2 += bflo(v0.y); a3 += bfhi(v0.y);
          a4 += bflo(v0.z); a5 += bfhi(v0.z);
          a6 += bflo(v0.w); a7 += bfhi(v0.w);
        }
      } else {
        const float* xs = (const float*)xsrc;
        for (; e + 2 < deg; e += 4) {
          int s0 = bp[e], s1 = bp[e + 2];
          const float4* r0 = (const float4*)(xs + (size_t)s0 * 128 + k0);
          const float4* r1 = (const float4*)(xs + (size_t)s1 * 128 + k0);
          float4 l0 = r0[0], h0 = r0[1];
          float4 l1 = r1[0], h1 = r1[1];
          a0 += l0.x + l1.x; a1 += l0.y + l1.y;
          a2 += l0.z + l1.z; a3 += l0.w + l1.w;
          a4 += h0.x + h1.x; a5 += h0.y + h1.y;
          a6 += h0.z + h1.z; a7 += h0.w + h1.w;
        }
        if (e < deg) {
          int s = bp[e];
          const float4* r = (const float4*)(xs + (size_t)s * 128 + k0);
          float4 l = r[0], h = r[1];
          a0 += l.x; a1 += l.y; a2 += l.z; a3 += l.w;
          a4 += h.x; a5 += h.y; a6 += h.z; a7 += h.w;
        }
      }
    }
    a0 += __shfl_xor(a0, 16); a1 += __shfl_xor(a1, 16);
    a2 += __shfl_xor(a2, 16); a3 += __shfl_xor(a3, 16);
    a4 += __shfl_xor(a4, 16); a5 += __shfl_xor(a5, 16);
    a6 += __shfl_xor(a6, 16); a7 += __shfl_xor(a7, 16);
    if (par == 0) {
      float sc = deg > 0 ? 1.0f / (float)deg : 0.f;
      uint4 p;
      p.x = (unsigned)f2bf(a0 * sc) | ((unsigned)f2bf(a1 * sc) << 16);
      p.y = (unsigned)f2bf(a2 * sc) | ((unsigned)f2bf(a3 * sc) << 16);
      p.z = (unsigned)f2bf(a4 * sc) | ((unsigned)f2bf(a5 * sc) << 16);
      p.w = (unsigned)f2bf(a6 * sc) | ((unsigned)f2bf(a7 * sc) << 16);
      int ks = slice >> 2, quad = slice & 3;
      int mt = m >> 4, mlo = m & 15;
      ldsA4[(mt * 4 + ks) * 64 + quad * 16 + (mlo ^ (slice & 7))] = p;
    }
  }
  __syncthreads();

  // ---- phase 4: MFMA agg half (k_global 0..127) ----
  #pragma unroll
  for (int kk = 0; kk < 4; ++kk) {
    short8 af = A[(wave * 4 + kk) * 64 + quadr * 16 + (mlor ^ ((kk * 4 + quadr) & 7))];
    #pragma unroll
    for (int nt = 0; nt < 8; ++nt) {
      short8 bf = B[(nt * 8 + kk) * 64 + lane];
      acc[nt] = __builtin_amdgcn_mfma_f32_16x16x32_bf16(af, bf, acc[nt], 0, 0, 0);
    }
  }
  __syncthreads();                               // all waves done reading ldsA4

  // ---- epilogue: bias+relu -> LDS transpose (per-wave 4KB region, 8-row
  //      halves) -> full-line coalesced NT stores (1024B/wave-instr) ----
  float* T = (float*)ldsA4 + wave * 1024;
  #pragma unroll
  for (int h = 0; h < 2; ++h) {
    __syncthreads();   // orders the two halves' LDS reuse block-wide
    if ((quadr >> 1) == h) {
      int rl = (quadr & 1) * 4;                  // local row base within half
      #pragma unroll
      for (int nt = 0; nt < 8; ++nt) {
        #pragma unroll
        for (int r2 = 0; r2 < 4; ++r2) {
          float v = acc[nt][r2] + bv[nt];
          T[(rl + r2) * 128 + nt * 16 + mlor] = v > 0.f ? v : 0.f;
        }
      }
    }
    // wave-synchronous: same wave wrote this region; DS pipe is in-order
    #pragma unroll
    for (int j = 0; j < 4; ++j) {
      int f = j * 256 + lane * 4;                // 4 consecutive floats
      f32x4 v = *(const f32x4*)&T[f];
      int node = node0 + wave * 16 + h * 8 + (f >> 7);
      if (node < nvalid) {
        f32x4* dst = (f32x4*)&outbase[(size_t)node * 128 + (f & 127)];
        __builtin_nontemporal_store(v, dst);
      }
    }
  }
}

// ---------------------------------------------------------------------------
// Workspace layout (bytes):
//   cnt_user @0 800000 | cnt_item @800000 400000
//   bkt_user @1200000 25600000  (200000*32*4)
//   bkt_item @26800000 19200000 (100000*48*4)
//   Wp_user @46000000 65536 | Wp_item @46065536 65536
//   bias_user @46131072 512 | bias_item @46131584 512
//   xb_user @46132096 51200000 | xb_item @97332096 25600000 | end 122932096
// ---------------------------------------------------------------------------
extern "C" void kernel_launch(void* const* d_in, const int* in_sizes, int n_in,
                              void* d_out, int out_size, void* d_ws, size_t ws_size,
                              hipStream_t stream)
{
  const float* x_user = (const float*)d_in[0];
  const float* x_item = (const float*)d_in[1];
  const int* esrc_ui  = (const int*)d_in[2];
  const int* edst_ui  = (const int*)d_in[3];
  const int* esrc_iu  = (const int*)d_in[4];
  const int* edst_iu  = (const int*)d_in[5];
  const float* Wl_ui  = (const float*)d_in[6];
  const float* bl_ui  = (const float*)d_in[7];
  const float* Wr_ui  = (const float*)d_in[8];
  const float* Wl_iu  = (const float*)d_in[9];
  const float* bl_iu  = (const float*)d_in[10];
  const float* Wr_iu  = (const float*)d_in[11];
  const float* W_user = (const float*)d_in[12];
  const float* b_user = (const float*)d_in[13];
  const float* W_item = (const float*)d_in[14];
  const float* b_item = (const float*)d_in[15];
  float* out = (float*)d_out;

  char* ws = (char*)d_ws;
  int* cnt_user  = (int*)(ws + 0);
  int* cnt_item  = (int*)(ws + 800000);
  int* bkt_user  = (int*)(ws + 1200000);
  int* bkt_item  = (int*)(ws + 26800000UL);
  unsigned short* Wp_user = (unsigned short*)(ws + 46000000UL);
  unsigned short* Wp_item = (unsigned short*)(ws + 46065536UL);
  float* bias_user = (float*)(ws + 46131072UL);
  float* bias_item = (float*)(ws + 46131584UL);
  unsigned short* xb_user = (unsigned short*)(ws + 46132096UL);
  unsigned short* xb_item = (unsigned short*)(ws + 97332096UL);

  const bool bf = ws_size >= 122932096UL;

  // zero only the degree counters (1.2 MB)
  (void)hipMemsetAsync(d_ws, 0, 1200000, stream);

  prep<<<bf ? PB_END : PB_CVU, 256, 0, stream>>>(
      esrc_iu, edst_iu, cnt_user, bkt_user,
      esrc_ui, edst_ui, cnt_item, bkt_item,
      Wl_iu, Wr_iu, Wl_ui, Wr_ui, W_user, W_item, Wp_user, Wp_item,
      bl_iu, b_user, bl_ui, b_item, bias_user, bias_item,
      x_user, x_item, xb_user, xb_item);

  if (bf) {
    fused_gemm<true><<<NB_USER + NB_ITEM, 256, 0, stream>>>(
        xb_user, xb_item, cnt_user, bkt_user, Wp_user, bias_user,
        xb_item, xb_user, cnt_item, bkt_item, Wp_item, bias_item, out);
  } else {
    fused_gemm<false><<<NB_USER + NB_ITEM, 256, 0, stream>>>(
        x_user, x_item, cnt_user, bkt_user, Wp_user, bias_user,
        x_item, x_user, cnt_item, bkt_item, Wp_item, bias_item, out);
  }
}

// Round 5
// 584.504 us; speedup vs baseline: 1.0388x; 1.0388x over previous
//
#include <hip/hip_runtime.h>

// Problem constants (from reference)
#define NUu 200000
#define NIi 100000
#define EE  600000
// D = H = 128

#define NB_USER 3125  // (NUu+63)/64
#define NB_ITEM 1563  // (NIi+63)/64

// Fixed-capacity neighbor buckets, COLUMN-MAJOR: bkt[slot*N + node].
// - build: scattered writes land in slot columns 0..7 (~3-6MB hot) -> L2-resident
// - gather: a block's 64 nodes share cache lines per slot -> ~logical fetch
// deg ~ Poisson(3) user / Poisson(6) item. P(deg>=32) ~ 1e-27, P(deg>=48) ~ 1e-30.
#define CAP_U 32
#define CAP_I 48

// prep kernel grid sections
#define PB_BKT_U  586         // 586*1024 >= EE   (user-dst buckets)
#define PB_BKT    1172        // + item-dst buckets
#define PB_W      1428        // + 256 fuse_weights blocks
#define PB_BIAS   1428        // single bias block id
#define PB_CVU    1429        // conv-user start (12500 blocks)
#define PB_CVI    13929       // conv-item start (6250 blocks)
#define PB_END    20179

typedef short short8 __attribute__((ext_vector_type(8)));
typedef float floatx4 __attribute__((ext_vector_type(4)));
typedef float f32x4 __attribute__((ext_vector_type(4)));   // NT-capable vec

// float -> bf16 bits, round-to-nearest-even
__device__ __forceinline__ unsigned short f2bf(float f) {
  union { float f; unsigned int u; } v; v.f = f;
  unsigned int r = v.u + 0x7FFFu + ((v.u >> 16) & 1u);
  return (unsigned short)(r >> 16);
}
// bf16 pair (packed in u32) -> f32
__device__ __forceinline__ float bflo(unsigned int u) { return __uint_as_float(u << 16); }
__device__ __forceinline__ float bfhi(unsigned int u) { return __uint_as_float(u & 0xFFFF0000u); }

// ---------------------------------------------------------------------------
// prep: ONE launch fusing all preprocessing; the latency-bound random-atomic
// bucket blocks overlap with streaming conversion / weight-fusion blocks:
//   [0,586)        user-dst buckets (col-major, slot=atomicAdd(cnt[dst]))
//   [586,1172)     item-dst buckets
//   [1172,1428)    fused weights W1=Wl@W2, W2=Wr@W2 -> bf16 MFMA B-frag layout
//                  elem = ((nt*8+ks)*64 + quad*16 + nlo)*8 + j,
//                  k = ks*32+quad*8+j, n = nt*16+nlo
//   {1428}         fused bias  bl@W2 + b2
//   [1429,13929)   x_user -> bf16 (NT loads: read-once fp32 must not evict xb)
//   [13929,20179)  x_item -> bf16
// Fallback (ws too small for bf16 arrays): launch only [0,1429).
// ---------------------------------------------------------------------------
__global__ __launch_bounds__(256) void prep(
    const int* __restrict__ esrc_iu, const int* __restrict__ edst_iu,
    int* __restrict__ cnt_user, int* __restrict__ bkt_user,
    const int* __restrict__ esrc_ui, const int* __restrict__ edst_ui,
    int* __restrict__ cnt_item, int* __restrict__ bkt_item,
    const float* __restrict__ Wl_iu, const float* __restrict__ Wr_iu,
    const float* __restrict__ Wl_ui, const float* __restrict__ Wr_ui,
    const float* __restrict__ W_user, const float* __restrict__ W_item,
    unsigned short* __restrict__ Wp_user, unsigned short* __restrict__ Wp_item,
    const float* __restrict__ bl_iu, const float* __restrict__ b_user,
    const float* __restrict__ bl_ui, const float* __restrict__ b_item,
    float* __restrict__ bias_user, float* __restrict__ bias_item,
    const float* __restrict__ x_user, const float* __restrict__ x_item,
    unsigned short* __restrict__ xb_user, unsigned short* __restrict__ xb_item)
{
  int b = blockIdx.x, t = threadIdx.x;
  if (b < PB_BKT) {
    // ---- neighbor buckets (hist + fill fused; no scan needed) ----
    bool uside = b < PB_BKT_U;
    const int* es = uside ? esrc_iu : esrc_ui;
    const int* ed = uside ? edst_iu : edst_ui;
    int* cnt      = uside ? cnt_user : cnt_item;
    int* bkt      = uside ? bkt_user : bkt_item;
    int cap       = uside ? CAP_U : CAP_I;
    int N         = uside ? NUu : NIi;
    int local     = uside ? b : b - PB_BKT_U;
    int idx = local * 1024 + t * 4;
    if (idx < EE) {                       // EE%4==0 -> whole int4 valid
      int4 s = *(const int4*)(es + idx);
      int4 d = *(const int4*)(ed + idx);
      int p0 = atomicAdd(&cnt[d.x], 1); if (p0 < cap) bkt[p0 * N + d.x] = s.x;
      int p1 = atomicAdd(&cnt[d.y], 1); if (p1 < cap) bkt[p1 * N + d.y] = s.y;
      int p2 = atomicAdd(&cnt[d.z], 1); if (p2 < cap) bkt[p2 * N + d.z] = s.z;
      int p3 = atomicAdd(&cnt[d.w], 1); if (p3 < cap) bkt[p3 * N + d.w] = s.w;
    }
  } else if (b < PB_W) {
    // ---- fused weights ----
    int flat = (b - PB_BKT) * 256 + t;    // 0..65535
    int h = flat & 127, d = (flat >> 7) & 127, m = flat >> 14;
    const float* A; const float* W; unsigned short* dst; int koff;
    switch (m) {
      case 0:  A = Wl_iu; W = W_user; dst = Wp_user; koff = 0;   break;
      case 1:  A = Wr_iu; W = W_user; dst = Wp_user; koff = 128; break;
      case 2:  A = Wl_ui; W = W_item; dst = Wp_item; koff = 0;   break;
      default: A = Wr_ui; W = W_item; dst = Wp_item; koff = 128; break;
    }
    float acc = 0.f;
    for (int k = 0; k < 128; ++k) acc += A[d * 128 + k] * W[k * 128 + h];
    int kg = koff + d;
    int ks = kg >> 5, quad = (kg >> 3) & 3, j = kg & 7;
    int nt = h >> 4, nlo = h & 15;
    dst[((nt * 8 + ks) * 64 + quad * 16 + nlo) * 8 + j] = f2bf(acc);
  } else if (b == PB_BIAS) {
    // ---- fused bias ----
    int pair = t >> 7, h = t & 127;
    const float* bl = pair ? bl_ui : bl_iu;
    const float* b2 = pair ? b_item : b_user;
    const float* W  = pair ? W_item : W_user;
    float* o        = pair ? bias_item : bias_user;
    float acc = b2[h];
    for (int k = 0; k < 128; ++k) acc += bl[k] * W[k * 128 + h];
    o[h] = acc;
  } else {
    // ---- fp32 -> bf16 conversion (exact block coverage) ----
    const float* src; unsigned short* dst; long base;
    if (b < PB_CVI) { src = x_user; dst = xb_user; base = (long)(b - PB_CVU) * 2048 + t * 8; }
    else            { src = x_item; dst = xb_item; base = (long)(b - PB_CVI) * 2048 + t * 8; }
    const f32x4* p4 = (const f32x4*)(src + base);
    f32x4 lo = __builtin_nontemporal_load(p4);
    f32x4 hi = __builtin_nontemporal_load(p4 + 1);
    uint4 p;
    p.x = (unsigned)f2bf(lo.x) | ((unsigned)f2bf(lo.y) << 16);
    p.y = (unsigned)f2bf(lo.z) | ((unsigned)f2bf(lo.w) << 16);
    p.z = (unsigned)f2bf(hi.x) | ((unsigned)f2bf(hi.y) << 16);
    p.w = (unsigned)f2bf(hi.z) | ((unsigned)f2bf(hi.w) << 16);
    *(uint4*)(dst + base) = p;
  }
}

// ---------------------------------------------------------------------------
// K3 v5: fused node kernel over column-major fixed-capacity buckets.
//  - deg = min(cnt[node], CAP); neighbor e of node at bkt[e*N + node]
//    (block's 64 nodes share lines per slot -> near-logical index fetch)
//  - BF=true: bf16 gather rows (256B), 77MB working set L3-resident
//  - epilogue: acc -> LDS transpose -> PLAIN cached f32x4 stores, 1024B
//    contiguous per wave-instr (L2 merges full 128B lines; NT stores measured
//    +2.6x write amplification on gfx950 in R2/R4 -> removed)
// mfma_f32_16x16x32_bf16 C/D: col=lane&15, row=(lane>>4)*4+reg   (m89/m91)
// ---------------------------------------------------------------------------
template<bool BF>
__global__ __launch_bounds__(256, 8) void fused_gemm(
    const void* __restrict__ xu_own, const void* __restrict__ xu_src,
    const int* __restrict__ cnt_u, const int* __restrict__ bkt_u,
    const unsigned short* __restrict__ Wp_u, const float* __restrict__ bias_u,
    const void* __restrict__ xi_own, const void* __restrict__ xi_src,
    const int* __restrict__ cnt_i, const int* __restrict__ bkt_i,
    const unsigned short* __restrict__ Wp_i, const float* __restrict__ bias_i,
    float* __restrict__ out)
{
  __shared__ __align__(16) uint4 ldsA4[1024];    // 16 KB packed A (half of K), reused by epilogue
  __shared__ int rb[64];                         // block node degrees
  int t = threadIdx.x;
  int b = blockIdx.x;

  const void* xown; const void* xsrc; const int* cntp; const int* bkt;
  const unsigned short* Wp; const float* bias; float* outbase; int nvalid; int node0; int cap;
  if (b < NB_USER) {
    xown = xu_own; xsrc = xu_src; cntp = cnt_u; bkt = bkt_u;
    Wp = Wp_u; bias = bias_u; outbase = out; nvalid = NUu; node0 = b * 64; cap = CAP_U;
  } else {
    xown = xi_own; xsrc = xi_src; cntp = cnt_i; bkt = bkt_i;
    Wp = Wp_i; bias = bias_i; outbase = out + (size_t)NUu * 128;
    nvalid = NIi; node0 = (b - NB_USER) * 64; cap = CAP_I;
  }

  // ---- phase 0: degrees ----
  if (t < 64) {
    int node = node0 + t;
    int c = node < nvalid ? cntp[node] : 0;
    rb[t] = c < cap ? c : cap;
  }

  // ---- phase 1: own-half (K=128..255) pack into swizzled A slots ----
  #pragma unroll
  for (int i = 0; i < 4; ++i) {
    int oid = t + i * 256;
    int m = oid >> 4;                            // node within block
    int oct = oid & 15;                          // 8-elem k-slice
    int node = node0 + m;
    uint4 p; p.x = 0u; p.y = 0u; p.z = 0u; p.w = 0u;
    if (node < nvalid) {
      if constexpr (BF) {
        p = *(const uint4*)((const unsigned short*)xown + (size_t)node * 128 + oct * 8);
      } else {
        const float4* p4 = (const float4*)((const float*)xown + (size_t)node * 128 + oct * 8);
        float4 lo = p4[0], hi = p4[1];
        p.x = (unsigned)f2bf(lo.x) | ((unsigned)f2bf(lo.y) << 16);
        p.y = (unsigned)f2bf(lo.z) | ((unsigned)f2bf(lo.w) << 16);
        p.z = (unsigned)f2bf(hi.x) | ((unsigned)f2bf(hi.y) << 16);
        p.w = (unsigned)f2bf(hi.z) | ((unsigned)f2bf(hi.w) << 16);
      }
    }
    int ks = oct >> 2, quad = oct & 3;
    int mt = m >> 4, mlo = m & 15;
    ldsA4[(mt * 4 + ks) * 64 + quad * 16 + (mlo ^ (oct & 7))] = p;
  }
  __syncthreads();

  // ---- phase 2: MFMA own half (k_global 128..255) ----
  int wave = t >> 6, lane = t & 63;
  int quadr = lane >> 4, mlor = lane & 15;
  floatx4 acc[8];
  #pragma unroll
  for (int i = 0; i < 8; ++i) acc[i] = (floatx4){0.f, 0.f, 0.f, 0.f};
  float bv[8];
  #pragma unroll
  for (int nt = 0; nt < 8; ++nt) bv[nt] = bias[nt * 16 + mlor];
  const short8* A = (const short8*)ldsA4;
  const short8* B = (const short8*)Wp;
  #pragma unroll
  for (int kk = 0; kk < 4; ++kk) {
    short8 af = A[(wave * 4 + kk) * 64 + quadr * 16 + (mlor ^ ((kk * 4 + quadr) & 7))];
    #pragma unroll
    for (int nt = 0; nt < 8; ++nt) {
      short8 bf = B[(nt * 8 + 4 + kk) * 64 + lane];
      acc[nt] = __builtin_amdgcn_mfma_f32_16x16x32_bf16(af, bf, acc[nt], 0, 0, 0);
    }
  }
  __syncthreads();                               // ldsA consumed, safe to refill

  // ---- phase 3: gather+mean over bucket columns, parity-split (32 lanes/node) ----
  #pragma unroll
  for (int i = 0; i < 8; ++i) {
    int oid = t + i * 256;
    int m = oid >> 5;
    int oct = oid & 31;
    int slice = oct & 15;
    int par = oct >> 4;
    int node = node0 + m;
    float a0=0,a1=0,a2=0,a3=0,a4=0,a5=0,a6=0,a7=0;
    int deg = rb[m];
    if (node < nvalid && deg > 0) {
      const int* bp = bkt + node;                // column base, stride nvalid
      int k0 = slice * 8;
      int e = par;
      if constexpr (BF) {
        const unsigned short* xs = (const unsigned short*)xsrc;
        for (; e + 2 < deg; e += 4) {
          int s0 = bp[e * nvalid], s1 = bp[(e + 2) * nvalid];
          uint4 v0 = *(const uint4*)(xs + (size_t)s0 * 128 + k0);
          uint4 v1 = *(const uint4*)(xs + (size_t)s1 * 128 + k0);
          a0 += bflo(v0.x) + bflo(v1.x); a1 += bfhi(v0.x) + bfhi(v1.x);
          a2 += bflo(v0.y) + bflo(v1.y); a3 += bfhi(v0.y) + bfhi(v1.y);
          a4 += bflo(v0.z) + bflo(v1.z); a5 += bfhi(v0.z) + bfhi(v1.z);
          a6 += bflo(v0.w) + bflo(v1.w); a7 += bfhi(v0.w) + bfhi(v1.w);
        }
        if (e < deg) {
          int s = bp[e * nvalid];
          uint4 v0 = *(const uint4*)(xs + (size_t)s * 128 + k0);
          a0 += bflo(v0.x); a1 += bfhi(v0.x);
          a2 += bflo(v0.y); a3 += bfhi(v0.y);
          a4 += bflo(v0.z); a5 += bfhi(v0.z);
          a6 += bflo(v0.w); a7 += bfhi(v0.w);
        }
      } else {
        const float* xs = (const float*)xsrc;
        for (; e + 2 < deg; e += 4) {
          int s0 = bp[e * nvalid], s1 = bp[(e + 2) * nvalid];
          const float4* r0 = (const float4*)(xs + (size_t)s0 * 128 + k0);
          const float4* r1 = (const float4*)(xs + (size_t)s1 * 128 + k0);
          float4 l0 = r0[0], h0 = r0[1];
          float4 l1 = r1[0], h1 = r1[1];
          a0 += l0.x + l1.x; a1 += l0.y + l1.y;
          a2 += l0.z + l1.z; a3 += l0.w + l1.w;
          a4 += h0.x + h1.x; a5 += h0.y + h1.y;
          a6 += h0.z + h1.z; a7 += h0.w + h1.w;
        }
        if (e < deg) {
          int s = bp[e * nvalid];
          const float4* r = (const float4*)(xs + (size_t)s * 128 + k0);
          float4 l = r[0], h = r[1];
          a0 += l.x; a1 += l.y; a2 += l.z; a3 += l.w;
          a4 += h.x; a5 += h.y; a6 += h.z; a7 += h.w;
        }
      }
    }
    a0 += __shfl_xor(a0, 16); a1 += __shfl_xor(a1, 16);
    a2 += __shfl_xor(a2, 16); a3 += __shfl_xor(a3, 16);
    a4 += __shfl_xor(a4, 16); a5 += __shfl_xor(a5, 16);
    a6 += __shfl_xor(a6, 16); a7 += __shfl_xor(a7, 16);
    if (par == 0) {
      float sc = deg > 0 ? 1.0f / (float)deg : 0.f;
      uint4 p;
      p.x = (unsigned)f2bf(a0 * sc) | ((unsigned)f2bf(a1 * sc) << 16);
      p.y = (unsigned)f2bf(a2 * sc) | ((unsigned)f2bf(a3 * sc) << 16);
      p.z = (unsigned)f2bf(a4 * sc) | ((unsigned)f2bf(a5 * sc) << 16);
      p.w = (unsigned)f2bf(a6 * sc) | ((unsigned)f2bf(a7 * sc) << 16);
      int ks = slice >> 2, quad = slice & 3;
      int mt = m >> 4, mlo = m & 15;
      ldsA4[(mt * 4 + ks) * 64 + quad * 16 + (mlo ^ (slice & 7))] = p;
    }
  }
  __syncthreads();

  // ---- phase 4: MFMA agg half (k_global 0..127) ----
  #pragma unroll
  for (int kk = 0; kk < 4; ++kk) {
    short8 af = A[(wave * 4 + kk) * 64 + quadr * 16 + (mlor ^ ((kk * 4 + quadr) & 7))];
    #pragma unroll
    for (int nt = 0; nt < 8; ++nt) {
      short8 bf = B[(nt * 8 + kk) * 64 + lane];
      acc[nt] = __builtin_amdgcn_mfma_f32_16x16x32_bf16(af, bf, acc[nt], 0, 0, 0);
    }
  }
  __syncthreads();                               // all waves done reading ldsA4

  // ---- epilogue: bias+relu -> LDS transpose (per-wave 4KB region, 8-row
  //      halves) -> full-line coalesced PLAIN stores (1024B/wave-instr) ----
  float* T = (float*)ldsA4 + wave * 1024;
  #pragma unroll
  for (int h = 0; h < 2; ++h) {
    __syncthreads();   // orders the two halves' LDS reuse block-wide
    if ((quadr >> 1) == h) {
      int rl = (quadr & 1) * 4;                  // local row base within half
      #pragma unroll
      for (int nt = 0; nt < 8; ++nt) {
        #pragma unroll
        for (int r2 = 0; r2 < 4; ++r2) {
          float v = acc[nt][r2] + bv[nt];
          T[(rl + r2) * 128 + nt * 16 + mlor] = v > 0.f ? v : 0.f;
        }
      }
    }
    // wave-synchronous: same wave wrote this region; DS pipe is in-order
    #pragma unroll
    for (int j = 0; j < 4; ++j) {
      int f = j * 256 + lane * 4;                // 4 consecutive floats
      f32x4 v = *(const f32x4*)&T[f];
      int node = node0 + wave * 16 + h * 8 + (f >> 7);
      if (node < nvalid) {
        *(f32x4*)&outbase[(size_t)node * 128 + (f & 127)] = v;
      }
    }
  }
}

// ---------------------------------------------------------------------------
// Workspace layout (bytes):
//   cnt_user @0 800000 | cnt_item @800000 400000
//   bkt_user @1200000 25600000  (32 slots x 200000, col-major)
//   bkt_item @26800000 19200000 (48 slots x 100000, col-major)
//   Wp_user @46000000 65536 | Wp_item @46065536 65536
//   bias_user @46131072 512 | bias_item @46131584 512
//   xb_user @46132096 51200000 | xb_item @97332096 25600000 | end 122932096
// ---------------------------------------------------------------------------
extern "C" void kernel_launch(void* const* d_in, const int* in_sizes, int n_in,
                              void* d_out, int out_size, void* d_ws, size_t ws_size,
                              hipStream_t stream)
{
  const float* x_user = (const float*)d_in[0];
  const float* x_item = (const float*)d_in[1];
  const int* esrc_ui  = (const int*)d_in[2];
  const int* edst_ui  = (const int*)d_in[3];
  const int* esrc_iu  = (const int*)d_in[4];
  const int* edst_iu  = (const int*)d_in[5];
  const float* Wl_ui  = (const float*)d_in[6];
  const float* bl_ui  = (const float*)d_in[7];
  const float* Wr_ui  = (const float*)d_in[8];
  const float* Wl_iu  = (const float*)d_in[9];
  const float* bl_iu  = (const float*)d_in[10];
  const float* Wr_iu  = (const float*)d_in[11];
  const float* W_user = (const float*)d_in[12];
  const float* b_user = (const float*)d_in[13];
  const float* W_item = (const float*)d_in[14];
  const float* b_item = (const float*)d_in[15];
  float* out = (float*)d_out;

  char* ws = (char*)d_ws;
  int* cnt_user  = (int*)(ws + 0);
  int* cnt_item  = (int*)(ws + 800000);
  int* bkt_user  = (int*)(ws + 1200000);
  int* bkt_item  = (int*)(ws + 26800000UL);
  unsigned short* Wp_user = (unsigned short*)(ws + 46000000UL);
  unsigned short* Wp_item = (unsigned short*)(ws + 46065536UL);
  float* bias_user = (float*)(ws + 46131072UL);
  float* bias_item = (float*)(ws + 46131584UL);
  unsigned short* xb_user = (unsigned short*)(ws + 46132096UL);
  unsigned short* xb_item = (unsigned short*)(ws + 97332096UL);

  const bool bf = ws_size >= 122932096UL;

  // zero only the degree counters (1.2 MB)
  (void)hipMemsetAsync(d_ws, 0, 1200000, stream);

  prep<<<bf ? PB_END : PB_CVU, 256, 0, stream>>>(
      esrc_iu, edst_iu, cnt_user, bkt_user,
      esrc_ui, edst_ui, cnt_item, bkt_item,
      Wl_iu, Wr_iu, Wl_ui, Wr_ui, W_user, W_item, Wp_user, Wp_item,
      bl_iu, b_user, bl_ui, b_item, bias_user, bias_item,
      x_user, x_item, xb_user, xb_item);

  if (bf) {
    fused_gemm<true><<<NB_USER + NB_ITEM, 256, 0, stream>>>(
        xb_user, xb_item, cnt_user, bkt_user, Wp_user, bias_user,
        xb_item, xb_user, cnt_item, bkt_item, Wp_item, bias_item, out);
  } else {
    fused_gemm<false><<<NB_USER + NB_ITEM, 256, 0, stream>>>(
        x_user, x_item, cnt_user, bkt_user, Wp_user, bias_user,
        x_item, x_user, cnt_item, bkt_item, Wp_item, bias_item, out);
  }
}

// Round 6
// 522.093 us; speedup vs baseline: 1.1630x; 1.1195x over previous
//
#include <hip/hip_runtime.h>

// Problem constants (from reference)
#define NUu 200000
#define NIi 100000
#define EE  600000
// D = H = 128

#define SCAP 768      // LDS src-index window (block windows avg 192/384; global fallback covers)
#define NB_USER 3125  // (NUu+63)/64
#define NB_ITEM 1563  // (NIi+63)/64
#define HB 586        // ceil(EE/1024) edge blocks

// conv_weights grid sections: [0,256) weights | {256} bias | [257,12757) conv user | [12757,19007) conv item
#define CW_BIAS 256
#define CW_CVU  257
#define CW_CVI  12757
#define CW_END  19007

typedef short short8 __attribute__((ext_vector_type(8)));
typedef float floatx4 __attribute__((ext_vector_type(4)));

// float -> bf16 bits, round-to-nearest-even
__device__ __forceinline__ unsigned short f2bf(float f) {
  union { float f; unsigned int u; } v; v.f = f;
  unsigned int r = v.u + 0x7FFFu + ((v.u >> 16) & 1u);
  return (unsigned short)(r >> 16);
}
// bf16 pair (packed in u32) -> f32
__device__ __forceinline__ float bflo(unsigned int u) { return __uint_as_float(u << 16); }
__device__ __forceinline__ float bfhi(unsigned int u) { return __uint_as_float(u & 0xFFFF0000u); }

// ---------------------------------------------------------------------------
// conv_weights: streaming preprocessing (no atomics)
//   [0,256)   fused weights W1=Wl@W2, W2=Wr@W2 -> bf16 MFMA B-frag layout
//             elem = ((nt*8+ks)*64 + quad*16 + nlo)*8 + j, k=ks*32+quad*8+j, n=nt*16+nlo
//   {256}     fused bias bl@W2 + b2
//   [257,...) x_user -> bf16, x_item -> bf16
// ---------------------------------------------------------------------------
__global__ __launch_bounds__(256) void conv_weights(
    const float* __restrict__ Wl_iu, const float* __restrict__ Wr_iu,
    const float* __restrict__ Wl_ui, const float* __restrict__ Wr_ui,
    const float* __restrict__ W_user, const float* __restrict__ W_item,
    unsigned short* __restrict__ Wp_user, unsigned short* __restrict__ Wp_item,
    const float* __restrict__ bl_iu, const float* __restrict__ b_user,
    const float* __restrict__ bl_ui, const float* __restrict__ b_item,
    float* __restrict__ bias_user, float* __restrict__ bias_item,
    const float* __restrict__ x_user, const float* __restrict__ x_item,
    unsigned short* __restrict__ xb_user, unsigned short* __restrict__ xb_item)
{
  int b = blockIdx.x, t = threadIdx.x;
  if (b < CW_BIAS) {
    // ---- fused weights ----
    int flat = b * 256 + t;               // 0..65535
    int h = flat & 127, d = (flat >> 7) & 127, m = flat >> 14;
    const float* A; const float* W; unsigned short* dst; int koff;
    switch (m) {
      case 0:  A = Wl_iu; W = W_user; dst = Wp_user; koff = 0;   break;
      case 1:  A = Wr_iu; W = W_user; dst = Wp_user; koff = 128; break;
      case 2:  A = Wl_ui; W = W_item; dst = Wp_item; koff = 0;   break;
      default: A = Wr_ui; W = W_item; dst = Wp_item; koff = 128; break;
    }
    float acc = 0.f;
    for (int k = 0; k < 128; ++k) acc += A[d * 128 + k] * W[k * 128 + h];
    int kg = koff + d;
    int ks = kg >> 5, quad = (kg >> 3) & 3, j = kg & 7;
    int nt = h >> 4, nlo = h & 15;
    dst[((nt * 8 + ks) * 64 + quad * 16 + nlo) * 8 + j] = f2bf(acc);
  } else if (b == CW_BIAS) {
    // ---- fused bias ----
    int pair = t >> 7, h = t & 127;
    const float* bl = pair ? bl_ui : bl_iu;
    const float* b2 = pair ? b_item : b_user;
    const float* W  = pair ? W_item : W_user;
    float* o        = pair ? bias_item : bias_user;
    float acc = b2[h];
    for (int k = 0; k < 128; ++k) acc += bl[k] * W[k * 128 + h];
    o[h] = acc;
  } else {
    // ---- fp32 -> bf16 conversion (exact block coverage) ----
    const float* src; unsigned short* dst; long base;
    if (b < CW_CVI) { src = x_user; dst = xb_user; base = (long)(b - CW_CVU) * 2048 + t * 8; }
    else            { src = x_item; dst = xb_item; base = (long)(b - CW_CVI) * 2048 + t * 8; }
    const float4* p4 = (const float4*)(src + base);
    float4 lo = p4[0], hi = p4[1];
    uint4 p;
    p.x = (unsigned)f2bf(lo.x) | ((unsigned)f2bf(lo.y) << 16);
    p.y = (unsigned)f2bf(lo.z) | ((unsigned)f2bf(lo.w) << 16);
    p.z = (unsigned)f2bf(hi.x) | ((unsigned)f2bf(hi.y) << 16);
    p.w = (unsigned)f2bf(hi.z) | ((unsigned)f2bf(hi.w) << 16);
    *(uint4*)(dst + base) = p;
  }
}

// ---------------------------------------------------------------------------
// hist_slots: histogram WITH slot memoization. The atomicAdd's return value
// (this edge's within-dst rank) is stored sequentially -> fill needs NO atomic.
// y=0: user-dst edges (iu), y=1: item-dst edges (ui).
// ---------------------------------------------------------------------------
__global__ __launch_bounds__(256) void hist_slots(
    const int* __restrict__ edst_iu, int* __restrict__ cnt_user, int* __restrict__ slots_user,
    const int* __restrict__ edst_ui, int* __restrict__ cnt_item, int* __restrict__ slots_item)
{
  int b = blockIdx.x, t = threadIdx.x;
  const int* ed = blockIdx.y ? edst_ui : edst_iu;
  int* cnt      = blockIdx.y ? cnt_item : cnt_user;
  int* slots    = blockIdx.y ? slots_item : slots_user;
  int idx = b * 1024 + t * 4;
  if (idx < EE) {                          // EE%4==0 -> whole int4 valid
    int4 d = *(const int4*)(ed + idx);
    int4 p;
    p.x = atomicAdd(&cnt[d.x], 1);
    p.y = atomicAdd(&cnt[d.y], 1);
    p.z = atomicAdd(&cnt[d.z], 1);
    p.w = atomicAdd(&cnt[d.w], 1);
    *(int4*)(slots + idx) = p;             // sequential streaming write
  }
}

// ---------------------------------------------------------------------------
// scan1: per-1024-chunk sums (user y=0 196 blocks, item y=1 98 blocks)
// ---------------------------------------------------------------------------
__global__ __launch_bounds__(256) void scan1(
    const int* __restrict__ cnt_u, int* __restrict__ blk_u,
    const int* __restrict__ cnt_i, int* __restrict__ blk_i)
{
  __shared__ int s[256];
  int b = blockIdx.x, t = threadIdx.x;
  const int* cnt; int* blksum; int N;
  if (blockIdx.y == 0) { cnt = cnt_u; blksum = blk_u; N = NUu; }
  else { if (b >= 98) return; cnt = cnt_i; blksum = blk_i; N = NIi; }
  int base = b * 1024 + t * 4;
  int v = 0;
  #pragma unroll
  for (int j = 0; j < 4; ++j) { int i = base + j; if (i < N) v += cnt[i]; }
  s[t] = v; __syncthreads();
  for (int off = 128; off > 0; off >>= 1) {
    if (t < off) s[t] += s[t + off];
    __syncthreads();
  }
  if (t == 0) blksum[b] = s[0];
}

// ---------------------------------------------------------------------------
// scan3: every block locally prefix-scans the block sums (<=196 values) to get
// its offset, then writes rowp for its 1024 nodes. (absorbs old scan2)
// ---------------------------------------------------------------------------
__global__ __launch_bounds__(256) void scan3(
    const int* __restrict__ cnt_u, const int* __restrict__ blks_u, int* __restrict__ row_u,
    const int* __restrict__ cnt_i, const int* __restrict__ blks_i, int* __restrict__ row_i)
{
  __shared__ int s[256];
  int b = blockIdx.x, t = threadIdx.x;
  const int* cnt; const int* blksum; int* rowp; int N; int nblk;
  if (blockIdx.y == 0) { cnt = cnt_u; blksum = blks_u; rowp = row_u; N = NUu; nblk = 196; }
  else { if (b >= 98) return; cnt = cnt_i; blksum = blks_i; rowp = row_i; N = NIi; nblk = 98; }

  int v2 = t < nblk ? blksum[t] : 0;
  s[t] = v2; __syncthreads();
  for (int off = 1; off < 256; off <<= 1) {
    int tmp = t >= off ? s[t - off] : 0;
    __syncthreads();
    s[t] += tmp;
    __syncthreads();
  }
  int blkoffb = (b == 0) ? 0 : s[b - 1];
  __syncthreads();

  int base = b * 1024 + t * 4;
  int v[4]; int sum = 0;
  #pragma unroll
  for (int j = 0; j < 4; ++j) { int i = base + j; v[j] = (i < N) ? cnt[i] : 0; sum += v[j]; }
  s[t] = sum; __syncthreads();
  for (int off = 1; off < 256; off <<= 1) {
    int tmp = t >= off ? s[t - off] : 0;
    __syncthreads();
    s[t] += tmp;
    __syncthreads();
  }
  int ex = s[t] - sum + blkoffb;
  #pragma unroll
  for (int j = 0; j < 4; ++j) {
    int i = base + j;
    if (i < N) { rowp[i] = ex; ex += v[j]; }
  }
}

// ---------------------------------------------------------------------------
// fill_ns: NON-ATOMIC CSR fill. position = rowp[dst] + memoized slot.
// ---------------------------------------------------------------------------
__global__ __launch_bounds__(256) void fill_ns(
    const int* __restrict__ esrc_iu, const int* __restrict__ edst_iu,
    const int* __restrict__ slots_u, const int* __restrict__ row_u, int* __restrict__ srcs_u,
    const int* __restrict__ esrc_ui, const int* __restrict__ edst_ui,
    const int* __restrict__ slots_i, const int* __restrict__ row_i, int* __restrict__ srcs_i)
{
  int b = blockIdx.x, t = threadIdx.x;
  const int* es; const int* ed; const int* sl; const int* rowp; int* srcs;
  if (blockIdx.y == 0) { es = esrc_iu; ed = edst_iu; sl = slots_u; rowp = row_u; srcs = srcs_u; }
  else                 { es = esrc_ui; ed = edst_ui; sl = slots_i; rowp = row_i; srcs = srcs_i; }
  int idx = b * 1024 + t * 4;
  if (idx < EE) {
    int4 s = *(const int4*)(es + idx);
    int4 d = *(const int4*)(ed + idx);
    int4 p = *(const int4*)(sl + idx);
    srcs[rowp[d.x] + p.x] = s.x;
    srcs[rowp[d.y] + p.y] = s.y;
    srcs[rowp[d.z] + p.z] = s.z;
    srcs[rowp[d.w] + p.w] = s.w;
  }
}

// ---------------------------------------------------------------------------
// K3 (R2-proven): fused node kernel.
//  BF=true: x arrays pre-converted to bf16 -> gather rows 256B (half traffic),
//  77MB working set is L3-resident, own-half pack is a raw 16B copy.
//  Output: NT scattered stores (bypass L3 -> protects bf16 gather residency;
//  measured best cfg: 194us, F253/W332 in R2).
//  SCAP 768 + launch_bounds(256,8): LDS 19.7KB -> 8 blocks/CU.
// mfma_f32_16x16x32_bf16 C/D: col=lane&15, row=(lane>>4)*4+reg   (m89/m91)
// ---------------------------------------------------------------------------
template<bool BF>
__global__ __launch_bounds__(256, 8) void fused_gemm(
    const void* __restrict__ xu_own, const void* __restrict__ xu_src,
    const int* __restrict__ rowp_u, const int* __restrict__ srcs_u,
    const unsigned short* __restrict__ Wp_u, const float* __restrict__ bias_u,
    const void* __restrict__ xi_own, const void* __restrict__ xi_src,
    const int* __restrict__ rowp_i, const int* __restrict__ srcs_i,
    const unsigned short* __restrict__ Wp_i, const float* __restrict__ bias_i,
    float* __restrict__ out)
{
  __shared__ __align__(16) uint4 ldsA4[1024];    // 16 KB packed A (half of K)
  __shared__ int ldsS[SCAP];                     // 3 KB src-index window
  __shared__ int rb[65];
  int t = threadIdx.x;
  int b = blockIdx.x;

  const void* xown; const void* xsrc; const int* rowp; const int* srcs;
  const unsigned short* Wp; const float* bias; float* outbase; int nvalid; int node0;
  if (b < NB_USER) {
    xown = xu_own; xsrc = xu_src; rowp = rowp_u; srcs = srcs_u;
    Wp = Wp_u; bias = bias_u; outbase = out; nvalid = NUu; node0 = b * 64;
  } else {
    xown = xi_own; xsrc = xi_src; rowp = rowp_i; srcs = srcs_i;
    Wp = Wp_i; bias = bias_i; outbase = out + (size_t)NUu * 128;
    nvalid = NIi; node0 = (b - NB_USER) * 64;
  }

  // ---- phase 0: row pointers + src-index window ----
  if (t < 65) {
    int node = node0 + t;
    rb[t] = node < nvalid ? rowp[node] : EE;
  }
  __syncthreads();
  int rs0 = rb[0];
  int W = rb[64] - rs0;
  for (int idx = t; idx < W && idx < SCAP; idx += 256)
    ldsS[idx] = srcs[rs0 + idx];

  // ---- phase 1: own-half (K=128..255) pack into swizzled A slots ----
  #pragma unroll
  for (int i = 0; i < 4; ++i) {
    int oid = t + i * 256;
    int m = oid >> 4;                            // node within block
    int oct = oid & 15;                          // 8-elem k-slice
    int node = node0 + m;
    uint4 p; p.x = 0u; p.y = 0u; p.z = 0u; p.w = 0u;
    if (node < nvalid) {
      if constexpr (BF) {
        p = *(const uint4*)((const unsigned short*)xown + (size_t)node * 128 + oct * 8);
      } else {
        const float4* p4 = (const float4*)((const float*)xown + (size_t)node * 128 + oct * 8);
        float4 lo = p4[0], hi = p4[1];
        p.x = (unsigned)f2bf(lo.x) | ((unsigned)f2bf(lo.y) << 16);
        p.y = (unsigned)f2bf(lo.z) | ((unsigned)f2bf(lo.w) << 16);
        p.z = (unsigned)f2bf(hi.x) | ((unsigned)f2bf(hi.y) << 16);
        p.w = (unsigned)f2bf(hi.z) | ((unsigned)f2bf(hi.w) << 16);
      }
    }
    int ks = oct >> 2, quad = oct & 3;
    int mt = m >> 4, mlo = m & 15;
    ldsA4[(mt * 4 + ks) * 64 + quad * 16 + (mlo ^ (oct & 7))] = p;
  }
  __syncthreads();

  // ---- phase 2: MFMA own half (k_global 128..255) ----
  int wave = t >> 6, lane = t & 63;
  int quadr = lane >> 4, mlor = lane & 15;
  floatx4 acc[8];
  #pragma unroll
  for (int i = 0; i < 8; ++i) acc[i] = (floatx4){0.f, 0.f, 0.f, 0.f};
  const short8* A = (const short8*)ldsA4;
  const short8* B = (const short8*)Wp;
  #pragma unroll
  for (int kk = 0; kk < 4; ++kk) {
    short8 af = A[(wave * 4 + kk) * 64 + quadr * 16 + (mlor ^ ((kk * 4 + quadr) & 7))];
    #pragma unroll
    for (int nt = 0; nt < 8; ++nt) {
      short8 bf = B[(nt * 8 + 4 + kk) * 64 + lane];
      acc[nt] = __builtin_amdgcn_mfma_f32_16x16x32_bf16(af, bf, acc[nt], 0, 0, 0);
    }
  }
  __syncthreads();                               // ldsA consumed, safe to refill

  // ---- phase 3: gather+mean, parity-split (all 32 lanes per node) ----
  #pragma unroll
  for (int i = 0; i < 8; ++i) {
    int oid = t + i * 256;
    int m = oid >> 5;
    int oct = oid & 31;
    int slice = oct & 15;
    int par = oct >> 4;
    int node = node0 + m;
    float a0=0,a1=0,a2=0,a3=0,a4=0,a5=0,a6=0,a7=0;
    int deg = 0;
    if (node < nvalid) {
      int erel = rb[m] - rs0;
      deg = rb[m + 1] - rb[m];
      int k0 = slice * 8;
      int e = par;
      if constexpr (BF) {
        const unsigned short* xs = (const unsigned short*)xsrc;
        for (; e + 2 < deg; e += 4) {
          int q0 = erel + e, q1 = q0 + 2;
          int s0 = (q0 < SCAP) ? ldsS[q0] : srcs[rs0 + q0];
          int s1 = (q1 < SCAP) ? ldsS[q1] : srcs[rs0 + q1];
          uint4 v0 = *(const uint4*)(xs + (size_t)s0 * 128 + k0);
          uint4 v1 = *(const uint4*)(xs + (size_t)s1 * 128 + k0);
          a0 += bflo(v0.x) + bflo(v1.x); a1 += bfhi(v0.x) + bfhi(v1.x);
          a2 += bflo(v0.y) + bflo(v1.y); a3 += bfhi(v0.y) + bfhi(v1.y);
          a4 += bflo(v0.z) + bflo(v1.z); a5 += bfhi(v0.z) + bfhi(v1.z);
          a6 += bflo(v0.w) + bflo(v1.w); a7 += bfhi(v0.w) + bfhi(v1.w);
        }
        if (e < deg) {
          int q = erel + e;
          int s = (q < SCAP) ? ldsS[q] : srcs[rs0 + q];
          uint4 v0 = *(const uint4*)(xs + (size_t)s * 128 + k0);
          a0 += bflo(v0.x); a1 += bfhi(v0.x);
          a2 += bflo(v0.y); a3 += bfhi(v0.y);
          a4 += bflo(v0.z); a5 += bfhi(v0.z);
          a6 += bflo(v0.w); a7 += bfhi(v0.w);
        }
      } else {
        const float* xs = (const float*)xsrc;
        for (; e + 2 < deg; e += 4) {
          int q0 = erel + e, q1 = q0 + 2;
          int s0 = (q0 < SCAP) ? ldsS[q0] : srcs[rs0 + q0];
          int s1 = (q1 < SCAP) ? ldsS[q1] : srcs[rs0 + q1];
          const float4* r0 = (const float4*)(xs + (size_t)s0 * 128 + k0);
          const float4* r1 = (const float4*)(xs + (size_t)s1 * 128 + k0);
          float4 l0 = r0[0], h0 = r0[1];
          float4 l1 = r1[0], h1 = r1[1];
          a0 += l0.x + l1.x; a1 += l0.y + l1.y;
          a2 += l0.z + l1.z; a3 += l0.w + l1.w;
          a4 += h0.x + h1.x; a5 += h0.y + h1.y;
          a6 += h0.z + h1.z; a7 += h0.w + h1.w;
        }
        if (e < deg) {
          int q = erel + e;
          int s = (q < SCAP) ? ldsS[q] : srcs[rs0 + q];
          const float4* r = (const float4*)(xs + (size_t)s * 128 + k0);
          float4 l = r[0], h = r[1];
          a0 += l.x; a1 += l.y; a2 += l.z; a3 += l.w;
          a4 += h.x; a5 += h.y; a6 += h.z; a7 += h.w;
        }
      }
    }
    a0 += __shfl_xor(a0, 16); a1 += __shfl_xor(a1, 16);
    a2 += __shfl_xor(a2, 16); a3 += __shfl_xor(a3, 16);
    a4 += __shfl_xor(a4, 16); a5 += __shfl_xor(a5, 16);
    a6 += __shfl_xor(a6, 16); a7 += __shfl_xor(a7, 16);
    if (par == 0) {
      float sc = deg > 0 ? 1.0f / (float)deg : 0.f;
      uint4 p;
      p.x = (unsigned)f2bf(a0 * sc) | ((unsigned)f2bf(a1 * sc) << 16);
      p.y = (unsigned)f2bf(a2 * sc) | ((unsigned)f2bf(a3 * sc) << 16);
      p.z = (unsigned)f2bf(a4 * sc) | ((unsigned)f2bf(a5 * sc) << 16);
      p.w = (unsigned)f2bf(a6 * sc) | ((unsigned)f2bf(a7 * sc) << 16);
      int ks = slice >> 2, quad = slice & 3;
      int mt = m >> 4, mlo = m & 15;
      ldsA4[(mt * 4 + ks) * 64 + quad * 16 + (mlo ^ (slice & 7))] = p;
    }
  }
  __syncthreads();

  // ---- phase 4: MFMA agg half (k_global 0..127) ----
  #pragma unroll
  for (int kk = 0; kk < 4; ++kk) {
    short8 af = A[(wave * 4 + kk) * 64 + quadr * 16 + (mlor ^ ((kk * 4 + quadr) & 7))];
    #pragma unroll
    for (int nt = 0; nt < 8; ++nt) {
      short8 bf = B[(nt * 8 + kk) * 64 + lane];
      acc[nt] = __builtin_amdgcn_mfma_f32_16x16x32_bf16(af, bf, acc[nt], 0, 0, 0);
    }
  }

  // ---- epilogue: bias + relu, NT scattered stores (out never re-read) ----
  int col = lane & 15, qrow = (lane >> 4) * 4;
  #pragma unroll
  for (int nt = 0; nt < 8; ++nt) {
    int n = nt * 16 + col;
    float bv = bias[n];
    #pragma unroll
    for (int r2 = 0; r2 < 4; ++r2) {
      int node = node0 + wave * 16 + qrow + r2;
      if (node < nvalid) {
        float v = acc[nt][r2] + bv;
        v = v > 0.f ? v : 0.f;
        __builtin_nontemporal_store(v, &outbase[(size_t)node * 128 + n]);
      }
    }
  }
}

// ---------------------------------------------------------------------------
// Workspace layout (bytes):
//   cnt_user @0 800000 | cnt_item @800000 400000
//   row_user @1200000 800000 | row_item @2000000 400000
//   slots_user @3600000 2400000 | slots_item @6000000 2400000
//   srcs_user @8400000 2400000 | srcs_item @10800000 2400000
//   blks_user @13200000 1024 | blks_item @13201024 1024
//   Wp_user @13202048 65536 | Wp_item @13267584 65536
//   bias_user @13333120 512 | bias_item @13333632 512
//   xb_user @13334144 51200000 | xb_item @64534144 25600000 | end 90134144
// ---------------------------------------------------------------------------
extern "C" void kernel_launch(void* const* d_in, const int* in_sizes, int n_in,
                              void* d_out, int out_size, void* d_ws, size_t ws_size,
                              hipStream_t stream)
{
  const float* x_user = (const float*)d_in[0];
  const float* x_item = (const float*)d_in[1];
  const int* esrc_ui  = (const int*)d_in[2];
  const int* edst_ui  = (const int*)d_in[3];
  const int* esrc_iu  = (const int*)d_in[4];
  const int* edst_iu  = (const int*)d_in[5];
  const float* Wl_ui  = (const float*)d_in[6];
  const float* bl_ui  = (const float*)d_in[7];
  const float* Wr_ui  = (const float*)d_in[8];
  const float* Wl_iu  = (const float*)d_in[9];
  const float* bl_iu  = (const float*)d_in[10];
  const float* Wr_iu  = (const float*)d_in[11];
  const float* W_user = (const float*)d_in[12];
  const float* b_user = (const float*)d_in[13];
  const float* W_item = (const float*)d_in[14];
  const float* b_item = (const float*)d_in[15];
  float* out = (float*)d_out;

  char* ws = (char*)d_ws;
  int* cnt_user   = (int*)(ws + 0);
  int* cnt_item   = (int*)(ws + 800000);
  int* row_user   = (int*)(ws + 1200000);
  int* row_item   = (int*)(ws + 2000000);
  int* slots_user = (int*)(ws + 3600000);
  int* slots_item = (int*)(ws + 6000000);
  int* srcs_user  = (int*)(ws + 8400000);
  int* srcs_item  = (int*)(ws + 10800000UL);
  int* blks_user  = (int*)(ws + 13200000UL);
  int* blks_item  = (int*)(ws + 13201024UL);
  unsigned short* Wp_user = (unsigned short*)(ws + 13202048UL);
  unsigned short* Wp_item = (unsigned short*)(ws + 13267584UL);
  float* bias_user = (float*)(ws + 13333120UL);
  float* bias_item = (float*)(ws + 13333632UL);
  unsigned short* xb_user = (unsigned short*)(ws + 13334144UL);
  unsigned short* xb_item = (unsigned short*)(ws + 64534144UL);

  const bool bf = ws_size >= 90134144UL;

  // zero only the histograms (1.2 MB)
  (void)hipMemsetAsync(d_ws, 0, 1200000, stream);

  conv_weights<<<bf ? CW_END : CW_CVU, 256, 0, stream>>>(
      Wl_iu, Wr_iu, Wl_ui, Wr_ui, W_user, W_item, Wp_user, Wp_item,
      bl_iu, b_user, bl_ui, b_item, bias_user, bias_item,
      x_user, x_item, xb_user, xb_item);

  hist_slots<<<dim3(HB, 2), 256, 0, stream>>>(
      edst_iu, cnt_user, slots_user, edst_ui, cnt_item, slots_item);

  scan1<<<dim3(196, 2), 256, 0, stream>>>(cnt_user, blks_user, cnt_item, blks_item);
  scan3<<<dim3(196, 2), 256, 0, stream>>>(cnt_user, blks_user, row_user,
                                          cnt_item, blks_item, row_item);

  fill_ns<<<dim3(HB, 2), 256, 0, stream>>>(
      esrc_iu, edst_iu, slots_user, row_user, srcs_user,
      esrc_ui, edst_ui, slots_item, row_item, srcs_item);

  if (bf) {
    fused_gemm<true><<<NB_USER + NB_ITEM, 256, 0, stream>>>(
        xb_user, xb_item, row_user, srcs_user, Wp_user, bias_user,
        xb_item, xb_user, row_item, srcs_item, Wp_item, bias_item, out);
  } else {
    fused_gemm<false><<<NB_USER + NB_ITEM, 256, 0, stream>>>(
        x_user, x_item, row_user, srcs_user, Wp_user, bias_user,
        x_item, x_user, row_item, srcs_item, Wp_item, bias_item, out);
  }
}